// Round 9
// baseline (254.605 us; speedup 1.0000x reference)
//
#include <hip/hip_runtime.h>
#include <cstdint>
#include <cstddef>

#define M_DIM 4096   // B*S
#define N_DIM 4096   // DOUT
#define K_DIM 4096   // DIN
#define BM 128
#define BN 128
#define BKB 128      // K-tile in BYTES (= 128 i8 elems); 128B LDS rows
#define KTILES (K_DIM / BKB)

typedef __attribute__((ext_vector_type(4))) int i32x4;

// async global->LDS, 16B per lane. LDS dest is wave-uniform base + lane*16.
__device__ __forceinline__ void async_copy16(const void* g, void* l) {
  __builtin_amdgcn_global_load_lds(
      (const __attribute__((address_space(1))) void*)g,
      (__attribute__((address_space(3))) void*)l,
      16, 0, 0);
}

__device__ __forceinline__ void wait_vm6() {
  asm volatile("s_waitcnt vmcnt(6)" ::: "memory");
}
__device__ __forceinline__ void wait_vm0() {
  asm volatile("s_waitcnt vmcnt(0)" ::: "memory");
}

// ---------------------------------------------------------------------------
// Fused convert kernel (from R5): blocks [0,4096) = convert_w, blocks
// [4096,8192) = convert_x. Both verified bodies, unchanged.
// ---------------------------------------------------------------------------
__global__ __launch_bounds__(256) void convert_fused(
    const float* __restrict__ x, signed char* __restrict__ xi,
    float* __restrict__ sx, float* __restrict__ rs,
    const int* __restrict__ q, signed char* __restrict__ qsT) {
  __shared__ __align__(16) int smem[64 * 68];  // 17408 B
  const int t = threadIdx.x;

  if (blockIdx.x < 4096) {
    // ---------------- convert_w body ---------------------------------------
    int(*qtile)[68] = (int(*)[68])smem;
    const int bid = blockIdx.x;
    const int k0 = (bid & 63) << 6;
    const int n0 = (bid >> 6) << 6;

    {
      const int c = t & 15;        // n-chunk (4 ints)
      const int r0 = t >> 4;       // k-row base
#pragma unroll
      for (int i = 0; i < 4; ++i) {
        const int r = r0 + i * 16;
        const int4 v =
            *(const int4*)(q + (size_t)(k0 + r) * N_DIM + n0 + c * 4);
        *(int4*)&qtile[r][c * 4] = v;
      }
    }
    __syncthreads();
    {
      const int kc = t & 15;   // k-chunk: rows kc*4 .. kc*4+3
      const int g = t >> 4;    // n-group: cols g*4 .. g*4+3
      int4 v[4];
#pragma unroll
      for (int i = 0; i < 4; ++i)
        v[i] = *(const int4*)&qtile[kc * 4 + i][g * 4];
#pragma unroll
      for (int j = 0; j < 4; ++j) {
        const int b0 = ((&v[0].x)[j] - 128) & 255;
        const int b1 = ((&v[1].x)[j] - 128) & 255;
        const int b2 = ((&v[2].x)[j] - 128) & 255;
        const int b3 = ((&v[3].x)[j] - 128) & 255;
        const int pk = b0 | (b1 << 8) | (b2 << 16) | (b3 << 24);
        *(int*)(qsT + (size_t)(n0 + g * 4 + j) * K_DIM + k0 + kc * 4) = pk;
      }
    }
  } else {
    // ---------------- convert_x body ---------------------------------------
    float* red = (float*)smem;
    const size_t row = blockIdx.x - 4096;
    const float* xr = x + row * (size_t)K_DIM;

    float4 v[4];
    float amax = 0.f;
#pragma unroll
    for (int i = 0; i < 4; ++i) {
      v[i] = *(const float4*)(xr + (i * 256 + t) * 4);
      amax = fmaxf(amax, fmaxf(fmaxf(fabsf(v[i].x), fabsf(v[i].y)),
                               fmaxf(fabsf(v[i].z), fabsf(v[i].w))));
    }
#pragma unroll
    for (int o = 32; o > 0; o >>= 1)
      amax = fmaxf(amax, __shfl_down(amax, o, 64));
    if ((t & 63) == 0) red[t >> 6] = amax;
    __syncthreads();
    amax = fmaxf(fmaxf(fmaxf(red[0], red[1]), fmaxf(red[2], red[3])), 1e-20f);
    const float inv = 127.f / amax;

    int ssum = 0;
    signed char* out = xi + row * (size_t)K_DIM;
#pragma unroll
    for (int i = 0; i < 4; ++i) {
      const int ia = __float2int_rn(v[i].x * inv);
      const int ib = __float2int_rn(v[i].y * inv);
      const int ic = __float2int_rn(v[i].z * inv);
      const int id = __float2int_rn(v[i].w * inv);
      ssum += ia + ib + ic + id;
      const int pk =
          (ia & 255) | ((ib & 255) << 8) | ((ic & 255) << 16) | (id << 24);
      *(int*)(out + (i * 256 + t) * 4) = pk;
    }
    float fs = (float)ssum;
#pragma unroll
    for (int o = 32; o > 0; o >>= 1) fs += __shfl_down(fs, o, 64);
    if ((t & 63) == 0) red[4 + (t >> 6)] = fs;
    __syncthreads();
    if (t == 0) {
      rs[row] = red[4] + red[5] + red[6] + red[7];
      sx[row] = amax * (1.f / 127.f);
    }
  }
}

// ---------------------------------------------------------------------------
// Kernel 3: 128x128-tile i8 GEMM, 2 blocks/CU (R9). R8's ping-pong reverted
// (regressed, as did R7's SGB: forced fine interleave loses ~15us to the
// burst schedule). R9 keeps R6's burst-read 2-barrier tile but shrinks the
// tile to 128^2 / 4 waves / 64KB LDS so TWO blocks fit per CU: two
// independent barrier domains desynchronize, so one block's MFMA region
// covers the other's read/stage region (m114 co-schedule; guide: 128^2 beats
// 256^2 at 2-barrier structures).
//
// Ledger (R6 arithmetic, re-verified for 4 units/tile x 2 loads/lane):
//   units per tile t: S[4t+0]=A0(t) rows 0-63, S[4t+1]=A1(t) rows 64-127,
//                     S[4t+2]=B0(t), S[4t+3]=B1(t)
//   at tile t: S0 = B1(t+1)->buf^1 (top), S123 = A0,A1,B0(t+2)->buf (mid).
//   Prologue stages S[0..6]; tile-top vmcnt(6) (=3 units outstanding) =>
//   landed through S[4t+3] => ALL of tile t resident at top.
// WAR audit: S0 overwrites B1(t-1) of buf^1 - its reads (top of t-1) are
//   lgkm-drained by t-1's mid lgkmcnt(0), which precedes t's top barrier.
//   S123 overwrite A0/A1/B0(t) of buf - ALL tile-t reads (every wave reads
//   its A-half and B-half at tile top, both kh chunks) are drained by the
//   explicit lgkmcnt(0) before the mid barrier (cheap: those reads were
//   issued 16 MFMAs earlier). This drain is REQUIRED here (unlike R6-256^2,
//   where the region split was by row groups): kh=1 chunks of the same rows
//   are consumed only in region 2.
// Per tile: {vm6; barrier; 16 ds_reads (av/bv both kh); S0; 16 MFMA kh=0;
//   lgkmcnt(0); barrier; S123; 16 MFMA kh=1}. 2 barriers, 1 vmcnt, 1 lgkm.
// ---------------------------------------------------------------------------
__global__ __launch_bounds__(256, 2) void gemm_kernel(
    const signed char* __restrict__ A,   // [M][K] i8
    const signed char* __restrict__ Bt,  // [N][K] i8
    const float* __restrict__ bias, const float* __restrict__ sx,
    const float* __restrict__ rs, const float* __restrict__ scale_p,
    const float* __restrict__ zp_p, float* __restrict__ C) {
  __shared__ __align__(16) signed char As[2][BM * BKB];  // 2 x 16 KB
  __shared__ __align__(16) signed char Bs[2][BN * BKB];  // 2 x 16 KB

  const int tid = threadIdx.x;
  const int wave = tid >> 6;   // 0..3
  const int lane = tid & 63;
  const int wm = wave >> 1;    // 0..1  (M half)
  const int wn = wave & 1;     // 0..1  (N half)

  // T1: XCD-aware bijective swizzle; grid=1024, 128 consecutive per XCD.
  const int swz = (blockIdx.x & 7) * 128 + (blockIdx.x >> 3);
  const int bm = swz & 31;   // M fastest within an XCD chunk -> B panel reuse
  const int bn = swz >> 5;
  const size_t m0 = (size_t)bm * BM;
  const size_t n0 = (size_t)bn * BN;

  // staging lane decomposition: LDS dest linear, global src pre-swizzled.
  const int srow = lane >> 3;                   // 0..7 row within 1KB issue
  const int schunk = (lane & 7) ^ srow;         // swizzled global 16B chunk

  // fragment lane decomposition (16x16x64)
  const int quad = lane >> 4;
  const int lrow = lane & 15;
  const int rsw = lrow & 7;

  const signed char* Abase = A + m0 * K_DIM + schunk * 16;
  const signed char* Bbase = Bt + n0 * K_DIM + schunk * 16;

  i32x4 acc[4][4];
  const i32x4 zero = {0, 0, 0, 0};
#pragma unroll
  for (int i = 0; i < 4; ++i)
#pragma unroll
    for (int j = 0; j < 4; ++j) acc[i][j] = zero;

  // Unit stagers: one unit = 64 rows x 128B = 8KB = 2 global_load_lds/lane.
  // 4 waves x 8 rows per issue x 2 issues = 64 rows.
  auto stageAu = [&](int b, int k0, int u) {
#pragma unroll
    for (int i = 0; i < 2; ++i) {
      const int rbase = u * 64 + i * 32 + wave * 8;  // wave-uniform
      const size_t go = (size_t)(rbase + srow) * K_DIM + k0;
      async_copy16(Abase + go, (void*)&As[b][rbase * BKB]);
    }
  };
  auto stageBu = [&](int b, int k0, int u) {
#pragma unroll
    for (int i = 0; i < 2; ++i) {
      const int rbase = u * 64 + i * 32 + wave * 8;
      const size_t go = (size_t)(rbase + srow) * K_DIM + k0;
      async_copy16(Bbase + go, (void*)&Bs[b][rbase * BKB]);
    }
  };

// 8 ds_read_b128 -> av[2][4]: this wave's A rows (wm half), both kh chunks.
#define LDA()                                                                \
  do {                                                                       \
    _Pragma("unroll") for (int kh = 0; kh < 2; ++kh)                         \
        _Pragma("unroll") for (int t = 0; t < 4; ++t) {                      \
      const int ar = wm * 64 + t * 16 + lrow;                                \
      av[kh][t] =                                                            \
          *(const i32x4*)(as + ar * BKB + ((((kh << 2) | quad) ^ rsw) << 4));\
    }                                                                        \
  } while (0)

#define LDB()                                                                \
  do {                                                                       \
    _Pragma("unroll") for (int kh = 0; kh < 2; ++kh)                         \
        _Pragma("unroll") for (int t = 0; t < 4; ++t) {                      \
      const int br = wn * 64 + t * 16 + lrow;                                \
      bv[kh][t] =                                                            \
          *(const i32x4*)(bs + br * BKB + ((((kh << 2) | quad) ^ rsw) << 4));\
    }                                                                        \
  } while (0)

// 16 MFMA: one kh slice, full 4x4 fragment grid.
#define MFMA_KH(kh)                                                          \
  do {                                                                       \
    __builtin_amdgcn_s_setprio(1);                                           \
    _Pragma("unroll") for (int t = 0; t < 4; ++t)                            \
        _Pragma("unroll") for (int j = 0; j < 4; ++j)                        \
        acc[t][j] = __builtin_amdgcn_mfma_i32_16x16x64_i8(                   \
            av[kh][t], bv[kh][j], acc[t][j], 0, 0, 0);                       \
    __builtin_amdgcn_s_setprio(0);                                           \
  } while (0)

  // One tile: 2 barriers, 1 vmcnt, 1 lgkm drain.
#define DO_TILE(AS, BS, TOPW, S0, S123)                                      \
  do {                                                                       \
    const signed char* as = (AS);                                            \
    const signed char* bs = (BS);                                            \
    i32x4 av[2][4], bv[2][4];                                                \
    TOPW();                                                                  \
    __builtin_amdgcn_s_barrier();                                            \
    LDA();                                                                   \
    LDB();                                                                   \
    S0;                                                                      \
    MFMA_KH(0);                                                              \
    __builtin_amdgcn_sched_barrier(0);                                       \
    asm volatile("s_waitcnt lgkmcnt(0)" ::: "memory");                       \
    __builtin_amdgcn_sched_barrier(0);                                       \
    __builtin_amdgcn_s_barrier();                                            \
    S123;                                                                    \
    MFMA_KH(1);                                                              \
  } while (0)

  // Prologue: S[0..6] = tile0 {A0,A1,B0,B1} + tile1 {A0,A1,B0}.
  stageAu(0, 0, 0);
  stageAu(0, 0, 1);
  stageBu(0, 0, 0);
  stageBu(0, 0, 1);
  stageAu(1, BKB, 0);
  stageAu(1, BKB, 1);
  stageBu(1, BKB, 0);

#pragma unroll 2
  for (int kt = 0; kt < KTILES - 2; ++kt) {
    const int buf = kt & 1;
    const int k1 = (kt + 1) * BKB;
    const int k2 = (kt + 2) * BKB;
    DO_TILE(As[buf], Bs[buf], wait_vm6,
            (stageBu(buf ^ 1, k1, 1)),                  // S0 = B1(t+1)
            (stageAu(buf, k2, 0), stageAu(buf, k2, 1),  // S1,S2 = A0,A1(t+2)
             stageBu(buf, k2, 0)));                     // S3 = B0(t+2)
  }

  // Tail: tile 30 (S0 = B1(31) = S[127]; top vm6 lands through S[123]),
  // tile 31 (top vm0, no stages).
  DO_TILE(As[0], Bs[0], wait_vm6, (stageBu(1, 31 * BKB, 1)), (void)0);
  DO_TILE(As[1], Bs[1], wait_vm0, (void)0, (void)0);

#undef LDA
#undef LDB
#undef MFMA_KH
#undef DO_TILE

  // Epilogue: y = a_m*accf + b_m + bias[n], a_m = scale*sx[m],
  // b_m = scale*sx[m]*(128-zp)*rs[m].
  const float scale = scale_p[0];
  const float c1 = 128.f - zp_p[0];
#pragma unroll
  for (int i = 0; i < 4; ++i) {
    const size_t mbase = m0 + wm * 64 + i * 16 + quad * 4;
    float am[4], bmv[4];
#pragma unroll
    for (int r = 0; r < 4; ++r) {
      const float a = scale * sx[mbase + r];
      am[r] = a;
      bmv[r] = a * c1 * rs[mbase + r];
    }
#pragma unroll
    for (int j = 0; j < 4; ++j) {
      const size_t n = n0 + wn * 64 + j * 16 + lrow;
      const float bv = bias[n];
#pragma unroll
      for (int r = 0; r < 4; ++r) {
        C[(mbase + r) * N_DIM + n] =
            fmaf(am[r], (float)acc[i][j][r], bmv[r] + bv);
      }
    }
  }
}

// ---------------------------------------------------------------------------
extern "C" void kernel_launch(void* const* d_in, const int* in_sizes, int n_in,
                              void* d_out, int out_size, void* d_ws,
                              size_t ws_size, hipStream_t stream) {
  const float* x = (const float*)d_in[0];
  const int* q = (const int*)d_in[1];
  const float* scale = (const float*)d_in[2];
  const float* zp = (const float*)d_in[3];
  const float* bias = (const float*)d_in[4];
  float* out = (float*)d_out;

  char* ws = (char*)d_ws;
  signed char* xi = (signed char*)ws;                           // 16 MB
  signed char* qsT = (signed char*)(ws + ((size_t)16 << 20));   // 16 MB
  float* sx = (float*)(ws + ((size_t)32 << 20));                // 16 KB
  float* rs = (float*)(ws + ((size_t)32 << 20) + (16 << 10));   // 16 KB

  convert_fused<<<8192, 256, 0, stream>>>(x, xi, sx, rs, q, qsT);
  gemm_kernel<<<1024, 256, 0, stream>>>(xi, qsT, bias, sx, rs, scale, zp, out);
}

// Round 10
// 239.347 us; speedup vs baseline: 1.0637x; 1.0637x over previous
//
#include <hip/hip_runtime.h>
#include <cstdint>
#include <cstddef>

#define M_DIM 4096   // B*S
#define N_DIM 4096   // DOUT
#define K_DIM 4096   // DIN
#define BM 256
#define BN 256
#define BKB 128      // K-tile in BYTES (= 128 i8 elems); 128B LDS rows
#define KTILES (K_DIM / BKB)

typedef __attribute__((ext_vector_type(4))) int i32x4;

// async global->LDS, 16B per lane. LDS dest is wave-uniform base + lane*16.
__device__ __forceinline__ void async_copy16(const void* g, void* l) {
  __builtin_amdgcn_global_load_lds(
      (const __attribute__((address_space(1))) void*)g,
      (__attribute__((address_space(3))) void*)l,
      16, 0, 0);
}

__device__ __forceinline__ void wait_vm6() {
  asm volatile("s_waitcnt vmcnt(6)" ::: "memory");
}
__device__ __forceinline__ void wait_vm0() {
  asm volatile("s_waitcnt vmcnt(0)" ::: "memory");
}

// ---------------------------------------------------------------------------
// Fused convert kernel (R5): blocks [0,4096) = convert_w, blocks
// [4096,8192) = convert_x. Both verified bodies, unchanged.
// ---------------------------------------------------------------------------
__global__ __launch_bounds__(256) void convert_fused(
    const float* __restrict__ x, signed char* __restrict__ xi,
    float* __restrict__ sx, float* __restrict__ rs,
    const int* __restrict__ q, signed char* __restrict__ qsT) {
  __shared__ __align__(16) int smem[64 * 68];  // 17408 B
  const int t = threadIdx.x;

  if (blockIdx.x < 4096) {
    // ---------------- convert_w body ---------------------------------------
    int(*qtile)[68] = (int(*)[68])smem;
    const int bid = blockIdx.x;
    const int k0 = (bid & 63) << 6;
    const int n0 = (bid >> 6) << 6;

    {
      const int c = t & 15;        // n-chunk (4 ints)
      const int r0 = t >> 4;       // k-row base
#pragma unroll
      for (int i = 0; i < 4; ++i) {
        const int r = r0 + i * 16;
        const int4 v =
            *(const int4*)(q + (size_t)(k0 + r) * N_DIM + n0 + c * 4);
        *(int4*)&qtile[r][c * 4] = v;
      }
    }
    __syncthreads();
    {
      const int kc = t & 15;   // k-chunk: rows kc*4 .. kc*4+3
      const int g = t >> 4;    // n-group: cols g*4 .. g*4+3
      int4 v[4];
#pragma unroll
      for (int i = 0; i < 4; ++i)
        v[i] = *(const int4*)&qtile[kc * 4 + i][g * 4];
#pragma unroll
      for (int j = 0; j < 4; ++j) {
        const int b0 = ((&v[0].x)[j] - 128) & 255;
        const int b1 = ((&v[1].x)[j] - 128) & 255;
        const int b2 = ((&v[2].x)[j] - 128) & 255;
        const int b3 = ((&v[3].x)[j] - 128) & 255;
        const int pk = b0 | (b1 << 8) | (b2 << 16) | (b3 << 24);
        *(int*)(qsT + (size_t)(n0 + g * 4 + j) * K_DIM + k0 + kc * 4) = pk;
      }
    }
  } else {
    // ---------------- convert_x body ---------------------------------------
    float* red = (float*)smem;
    const size_t row = blockIdx.x - 4096;
    const float* xr = x + row * (size_t)K_DIM;

    float4 v[4];
    float amax = 0.f;
#pragma unroll
    for (int i = 0; i < 4; ++i) {
      v[i] = *(const float4*)(xr + (i * 256 + t) * 4);
      amax = fmaxf(amax, fmaxf(fmaxf(fabsf(v[i].x), fabsf(v[i].y)),
                               fmaxf(fabsf(v[i].z), fabsf(v[i].w))));
    }
#pragma unroll
    for (int o = 32; o > 0; o >>= 1)
      amax = fmaxf(amax, __shfl_down(amax, o, 64));
    if ((t & 63) == 0) red[t >> 6] = amax;
    __syncthreads();
    amax = fmaxf(fmaxf(fmaxf(red[0], red[1]), fmaxf(red[2], red[3])), 1e-20f);
    const float inv = 127.f / amax;

    int ssum = 0;
    signed char* out = xi + row * (size_t)K_DIM;
#pragma unroll
    for (int i = 0; i < 4; ++i) {
      const int ia = __float2int_rn(v[i].x * inv);
      const int ib = __float2int_rn(v[i].y * inv);
      const int ic = __float2int_rn(v[i].z * inv);
      const int id = __float2int_rn(v[i].w * inv);
      ssum += ia + ib + ic + id;
      const int pk =
          (ia & 255) | ((ib & 255) << 8) | ((ic & 255) << 16) | (id << 24);
      *(int*)(out + (i * 256 + t) * 4) = pk;
    }
    float fs = (float)ssum;
#pragma unroll
    for (int o = 32; o > 0; o >>= 1) fs += __shfl_down(fs, o, 64);
    if ((t & 63) == 0) red[4 + (t >> 6)] = fs;
    __syncthreads();
    if (t == 0) {
      rs[row] = red[4] + red[5] + red[6] + red[7];
      sx[row] = amax * (1.f / 127.f);
    }
  }
}

// ---------------------------------------------------------------------------
// Kernel 3: 256x256 i8 GEMM — EXACT R6 restore (verified best: 68.5 us,
// MfmaUtil 41%, 0 bank conflicts, FETCH 74 MB). 2 barriers + 1 vmcnt per
// tile, burst reads, counted-vmcnt ledger. R7 (SGB pinning), R8 (register
// ping-pong), R9 (128^2 2-blocks/CU) each regressed ~15 us — the burst
// schedule under compiler lgkm waits is the local optimum for this ledger.
//
// Ledger (R2-verified): half-tile staging order per tile t:
//   S[4t+0]=A_lo(t)  S[4t+1]=B_0(t)  S[4t+2]=B_1(t)  S[4t+3]=A_hi(t)
// S0 = A_hi(t+1)->buf^1 at tile top; S123 = A_lo/B_0/B_1(t+2)->buf after the
// mid barrier. Tile-top vmcnt(6) => all of tile t LDS-resident.
// TOP barrier fences S0 (overwrites A_hi(t-1) of buf^1, consumed by q2/q3 of
// t-1). MID barrier fences S123 (overwrite A_lo/B0/B1(t), whose tile-top
// ds_reads were data-consumed by q0/q1 => lgkm drained). A_hi reads (LDA(1),
// issued before the mid barrier) straddle it un-drained — legal: S123 does
// not touch the A_hi region; their overwriter S0(t+1) is fenced by the next
// TOP barrier after q2/q3 consumed them.
// ---------------------------------------------------------------------------
__global__ __launch_bounds__(512, 2) void gemm_kernel(
    const signed char* __restrict__ A,   // [M][K] i8
    const signed char* __restrict__ Bt,  // [N][K] i8
    const float* __restrict__ bias, const float* __restrict__ sx,
    const float* __restrict__ rs, const float* __restrict__ scale_p,
    const float* __restrict__ zp_p, float* __restrict__ C) {
  __shared__ __align__(16) signed char As[2][BM * BKB];  // 2 x 32 KB
  __shared__ __align__(16) signed char Bs[2][BN * BKB];  // 2 x 32 KB

  const int tid = threadIdx.x;
  const int wave = tid >> 6;   // 0..7
  const int lane = tid & 63;
  const int wm = wave >> 2;    // 0..1  (M half)
  const int wn = wave & 3;     // 0..3  (N quarter)

  // T1: XCD-aware bijective swizzle; grid=256, 32 consecutive per XCD.
  const int swz = (blockIdx.x & 7) * 32 + (blockIdx.x >> 3);
  const int bm = swz & 15;
  const int bn = swz >> 4;
  const size_t m0 = (size_t)bm * BM;
  const size_t n0 = (size_t)bn * BN;

  // staging lane decomposition: LDS dest linear, global src pre-swizzled.
  const int srow = lane >> 3;                   // 0..7 row within 1KB issue
  const int schunk = (lane & 7) ^ srow;         // swizzled global 16B chunk

  // fragment lane decomposition (16x16x64)
  const int quad = lane >> 4;
  const int lrow = lane & 15;
  const int rsw = lrow & 7;

  const signed char* Abase = A + m0 * K_DIM + schunk * 16;
  const signed char* Bbase = Bt + n0 * K_DIM + schunk * 16;

  i32x4 acc[8][4];
  const i32x4 zero = {0, 0, 0, 0};
#pragma unroll
  for (int i = 0; i < 8; ++i)
#pragma unroll
    for (int j = 0; j < 4; ++j) acc[i][j] = zero;

  // Half-tile stagers: each = 2 global_load_lds per lane (16 KB total).
  auto stageA = [&](int b, int k0, int ig) {
#pragma unroll
    for (int i = 0; i < 2; ++i) {
      const int rbase = i * 128 + ig * 64 + wave * 8;  // wave-uniform
      const size_t go = (size_t)(rbase + srow) * K_DIM + k0;
      async_copy16(Abase + go, (void*)&As[b][rbase * BKB]);
    }
  };
  auto stageB = [&](int b, int k0, int jg) {
#pragma unroll
    for (int i = 0; i < 2; ++i) {
      const int rbase = (i * 2 + (wave >> 2)) * 64 + jg * 32 + (wave & 3) * 8;
      const size_t go = (size_t)(rbase + srow) * K_DIM + k0;
      async_copy16(Bbase + go, (void*)&Bs[b][rbase * BKB]);
    }
  };

#define LDA(ig)                                                              \
  do {                                                                       \
    _Pragma("unroll") for (int kh = 0; kh < 2; ++kh)                         \
        _Pragma("unroll") for (int t = 0; t < 4; ++t) {                      \
      const int ar = wm * 128 + (ig) * 64 + t * 16 + lrow;                   \
      av[kh][t] =                                                            \
          *(const i32x4*)(as + ar * BKB + ((((kh << 2) | quad) ^ rsw) << 4));\
    }                                                                        \
  } while (0)

#define LDB(jg)                                                              \
  do {                                                                       \
    _Pragma("unroll") for (int kh = 0; kh < 2; ++kh)                         \
        _Pragma("unroll") for (int t = 0; t < 2; ++t) {                      \
      const int br = wn * 64 + ((jg) * 2 + t) * 16 + lrow;                   \
      bv[kh][(jg) * 2 + t] =                                                 \
          *(const i32x4*)(bs + br * BKB + ((((kh << 2) | quad) ^ rsw) << 4));\
    }                                                                        \
  } while (0)

#define MFMA16(ibase, j0)                                                    \
  do {                                                                       \
    _Pragma("unroll") for (int kh = 0; kh < 2; ++kh)                         \
        _Pragma("unroll") for (int t = 0; t < 4; ++t)                        \
            _Pragma("unroll") for (int j = 0; j < 2; ++j)                    \
        acc[(ibase) + t][(j0) + j] = __builtin_amdgcn_mfma_i32_16x16x64_i8(  \
            av[kh][t], bv[kh][(j0) + j], acc[(ibase) + t][(j0) + j], 0, 0,   \
            0);                                                              \
  } while (0)

  // One tile: 2 barriers, 1 vmcnt. S0 = A_hi(t+1) stage (top), S123 =
  // A_lo/B0/B1(t+2) stages (after mid barrier).
#define DO_TILE(AS, BS, TOPW, S0, S123)                                      \
  do {                                                                       \
    const signed char* as = (AS);                                            \
    const signed char* bs = (BS);                                            \
    i32x4 av[2][4], bv[2][4];                                                \
    TOPW();                                                                  \
    __builtin_amdgcn_s_barrier();                                            \
    LDA(0);                                                                  \
    LDB(0);                                                                  \
    LDB(1);                                                                  \
    S0;                                                                      \
    __builtin_amdgcn_s_setprio(1);                                           \
    MFMA16(0, 0); /* q0: A_lo x B0 */                                        \
    MFMA16(0, 2); /* q1: A_lo x B1 */                                        \
    __builtin_amdgcn_s_setprio(0);                                           \
    LDA(1);       /* av <- A_hi (reg WAR vs q0/q1; LDS src resident) */      \
    __builtin_amdgcn_s_barrier();                                            \
    S123;                                                                    \
    __builtin_amdgcn_s_setprio(1);                                           \
    MFMA16(4, 2); /* q2: A_hi x B1 */                                        \
    MFMA16(4, 0); /* q3: A_hi x B0 */                                        \
    __builtin_amdgcn_s_setprio(0);                                           \
  } while (0)

  // Prologue: stage units 1..7 = tile0 {A_lo,B_0,B_1,A_hi} + tile1
  // {A_lo,B_0,B_1}; tile 0's top vmcnt(6) lands through A_hi(0).
  stageA(0, 0, 0);
  stageB(0, 0, 0);
  stageB(0, 0, 1);
  stageA(0, 0, 1);
  stageA(1, BKB, 0);
  stageB(1, BKB, 0);
  stageB(1, BKB, 1);

#pragma unroll 2
  for (int kt = 0; kt < KTILES - 2; ++kt) {
    const int buf = kt & 1;
    const int k1 = (kt + 1) * BKB;
    const int k2 = (kt + 2) * BKB;
    DO_TILE(As[buf], Bs[buf], wait_vm6,
            (stageA(buf ^ 1, k1, 1)),                 // S0 = A_hi(t+1)
            (stageA(buf, k2, 0), stageB(buf, k2, 0),  // S1,S2 = A_lo,B0(t+2)
             stageB(buf, k2, 1)));                    // S3 = B_1(t+2)
  }

  // Tail: tile 30 (S0 = A_hi(31), no S123; top vmcnt(6) lands through
  // A_hi(30)), tile 31 (top vmcnt(0), no stages).
  DO_TILE(As[0], Bs[0], wait_vm6, (stageA(1, 31 * BKB, 1)), (void)0);
  DO_TILE(As[1], Bs[1], wait_vm0, (void)0, (void)0);

#undef LDA
#undef LDB
#undef MFMA16
#undef DO_TILE

  // Epilogue: y = a_m*accf + b_m + bias[n], a_m = scale*sx[m],
  // b_m = scale*sx[m]*(128-zp)*rs[m].
  const float scale = scale_p[0];
  const float c1 = 128.f - zp_p[0];
#pragma unroll
  for (int i = 0; i < 8; ++i) {
    const size_t mbase = m0 + wm * 128 + i * 16 + quad * 4;
    float am[4], bmv[4];
#pragma unroll
    for (int r = 0; r < 4; ++r) {
      const float a = scale * sx[mbase + r];
      am[r] = a;
      bmv[r] = a * c1 * rs[mbase + r];
    }
#pragma unroll
    for (int j = 0; j < 4; ++j) {
      const size_t n = n0 + wn * 64 + j * 16 + lrow;
      const float bv = bias[n];
#pragma unroll
      for (int r = 0; r < 4; ++r) {
        C[(mbase + r) * N_DIM + n] =
            fmaf(am[r], (float)acc[i][j][r], bmv[r] + bv);
      }
    }
  }
}

// ---------------------------------------------------------------------------
extern "C" void kernel_launch(void* const* d_in, const int* in_sizes, int n_in,
                              void* d_out, int out_size, void* d_ws,
                              size_t ws_size, hipStream_t stream) {
  const float* x = (const float*)d_in[0];
  const int* q = (const int*)d_in[1];
  const float* scale = (const float*)d_in[2];
  const float* zp = (const float*)d_in[3];
  const float* bias = (const float*)d_in[4];
  float* out = (float*)d_out;

  char* ws = (char*)d_ws;
  signed char* xi = (signed char*)ws;                           // 16 MB
  signed char* qsT = (signed char*)(ws + ((size_t)16 << 20));   // 16 MB
  float* sx = (float*)(ws + ((size_t)32 << 20));                // 16 KB
  float* rs = (float*)(ws + ((size_t)32 << 20) + (16 << 10));   // 16 KB

  convert_fused<<<8192, 256, 0, stream>>>(x, xi, sx, rs, q, qsT);
  gemm_kernel<<<256, 512, 0, stream>>>(xi, qsT, bias, sx, rs, scale, zp, out);
}